// Round 1
// baseline (292.888 us; speedup 1.0000x reference)
//
#include <hip/hip_runtime.h>

#define S_LEN 2048
#define HDIM  64
#define NHEAD 32
#define NBATCH 4
#define QBLK 64
#define KBLK 64
#define NEG_BIG (-1e30f)
// fold 1/sqrt(64) and log2(e) into Q so softmax uses exp2
#define QK_SCALE (0.125f * 1.44269504088896341f)

typedef float f32x4 __attribute__((ext_vector_type(4)));
typedef short bf16x8 __attribute__((ext_vector_type(8)));

static __device__ __forceinline__ unsigned short f2bf(float f) {
    unsigned int u = __float_as_uint(f);
    u += 0x7FFF + ((u >> 16) & 1);   // RNE
    return (unsigned short)(u >> 16);
}

// ---------------- pre-kernel 1: first unmasked key per batch ----------------
__global__ void firstzero_kernel(const int* __restrict__ masks, int* __restrict__ Lb) {
    const int b = blockIdx.x;
    const int t = threadIdx.x;
    __shared__ int smin;
    if (t == 0) smin = S_LEN;
    __syncthreads();
    int local = S_LEN;
    for (int k = t; k < S_LEN; k += 256) {
        if (masks[b * S_LEN + k] == 0) { local = k; break; }
    }
    atomicMin(&smin, local);
    __syncthreads();
    if (t == 0) Lb[b] = smin;
}

// ---------------- pre-kernel 2: per-head mean of V over keys ----------------
__global__ void meanv_kernel(const float* __restrict__ V, float* __restrict__ meanV) {
    const int bh = blockIdx.x;
    const int t = threadIdx.x;
    const int d = t & 63;
    const int part = t >> 6;  // 0..3
    const float* Vb = V + (size_t)bh * S_LEN * HDIM;
    float s = 0.f;
    const int k0 = part * (S_LEN / 4);
    for (int k = k0; k < k0 + S_LEN / 4; ++k) s += Vb[(size_t)k * HDIM + d];
    __shared__ float red[4][64];
    red[part][d] = s;
    __syncthreads();
    if (t < 64) {
        float tot = red[0][t] + red[1][t] + red[2][t] + red[3][t];
        meanV[bh * HDIM + t] = tot * (1.0f / (float)S_LEN);
    }
}

// ---------------- main flash-attention kernel ----------------
// LDS layout (bytes)
#define KT_OFF 0          // K tile  [64 key][64 d] bf16, swizzled
#define VT_OFF 8192       // V^T tile [64 d][64 key] bf16, swizzled
#define P_OFF  16384      // P per wave [16 q][64 key] bf16, swizzled (4 waves x 2KB)
#define SM_OFF 24576      // key-mask additive values, 64 floats
#define LDS_BYTES (24576 + 256)

__global__ __launch_bounds__(256) void attn_fwd(
    const float* __restrict__ Q, const float* __restrict__ K,
    const float* __restrict__ V, const int* __restrict__ masks,
    const float* __restrict__ meanV, const int* __restrict__ Lb,
    float* __restrict__ out)
{
    __shared__ __align__(16) char lds[LDS_BYTES];
    const int tid  = threadIdx.x;
    const int lane = tid & 63;
    const int w    = tid >> 6;           // wave 0..3
    const int qb   = blockIdx.x;
    const int bh   = blockIdx.y;
    const int q0   = qb * QBLK;
    const int b    = bh & (NBATCH - 1);  // tile-by-repeat: row bh uses masks[bh % 4]

    const size_t head_off = (size_t)bh * S_LEN * HDIM;
    const float* Qh = Q + head_off;
    const float* Kh = K + head_off;
    const float* Vh = V + head_off;

    const int lq = lane & 15;   // 0..15
    const int lk = lane >> 4;   // 0..3

    // ---- Q fragments (A layout: row = lane%16, k = 8*(lane>>4)+j, 2 chunks over D=64)
    bf16x8 qf[2];
    {
        const float* qrow = Qh + (size_t)(q0 + w * 16 + lq) * HDIM;
        #pragma unroll
        for (int c = 0; c < 2; ++c) {
            const int d0 = lk * 8 + c * 32;
            float4 f0 = *(const float4*)(qrow + d0);
            float4 f1 = *(const float4*)(qrow + d0 + 4);
            bf16x8 v;
            v[0] = (short)f2bf(f0.x * QK_SCALE); v[1] = (short)f2bf(f0.y * QK_SCALE);
            v[2] = (short)f2bf(f0.z * QK_SCALE); v[3] = (short)f2bf(f0.w * QK_SCALE);
            v[4] = (short)f2bf(f1.x * QK_SCALE); v[5] = (short)f2bf(f1.y * QK_SCALE);
            v[6] = (short)f2bf(f1.z * QK_SCALE); v[7] = (short)f2bf(f1.w * QK_SCALE);
            qf[c] = v;
        }
    }

    f32x4 acc_o[4];
    #pragma unroll
    for (int g = 0; g < 4; ++g) acc_o[g] = (f32x4){0.f, 0.f, 0.f, 0.f};
    float m_r[4] = {-__builtin_inff(), -__builtin_inff(), -__builtin_inff(), -__builtin_inff()};
    float l_r[4] = {0.f, 0.f, 0.f, 0.f};

    const int ntiles = qb + 1;  // causal: keys up to q0+63
    for (int t = 0; t < ntiles; ++t) {
        const int k0 = t * KBLK;
        __syncthreads();  // everyone done reading previous tile's LDS

        // ---- stage K tile: [key][d] bf16 swizzled; coalesced 64B/thread
        {
            const int r  = tid >> 2;          // key row 0..63
            const int cg = (tid & 3) << 4;    // f32 col 0/16/32/48
            const float* src = Kh + (size_t)(k0 + r) * HDIM + cg;
            float4 a0 = *(const float4*)(src);
            float4 a1 = *(const float4*)(src + 4);
            float4 a2 = *(const float4*)(src + 8);
            float4 a3 = *(const float4*)(src + 12);
            bf16x8 v0, v1;
            v0[0]=(short)f2bf(a0.x); v0[1]=(short)f2bf(a0.y); v0[2]=(short)f2bf(a0.z); v0[3]=(short)f2bf(a0.w);
            v0[4]=(short)f2bf(a1.x); v0[5]=(short)f2bf(a1.y); v0[6]=(short)f2bf(a1.z); v0[7]=(short)f2bf(a1.w);
            v1[0]=(short)f2bf(a2.x); v1[1]=(short)f2bf(a2.y); v1[2]=(short)f2bf(a2.z); v1[3]=(short)f2bf(a2.w);
            v1[4]=(short)f2bf(a3.x); v1[5]=(short)f2bf(a3.y); v1[6]=(short)f2bf(a3.z); v1[7]=(short)f2bf(a3.w);
            const int swz = (r & 7) << 4;
            *(bf16x8*)&lds[KT_OFF + ((r * 128 + cg * 2     ) ^ swz)] = v0;
            *(bf16x8*)&lds[KT_OFF + ((r * 128 + cg * 2 + 16) ^ swz)] = v1;
        }
        // ---- stage V^T tile: Vt[d][key] bf16 swizzled (scalar scatter writes)
        {
            const int kk = tid >> 2;          // key 0..63
            const int dg = (tid & 3) << 4;    // d base
            const float* src = Vh + (size_t)(k0 + kk) * HDIM + dg;
            float4 a0 = *(const float4*)(src);
            float4 a1 = *(const float4*)(src + 4);
            float4 a2 = *(const float4*)(src + 8);
            float4 a3 = *(const float4*)(src + 12);
            float vals[16] = {a0.x,a0.y,a0.z,a0.w, a1.x,a1.y,a1.z,a1.w,
                              a2.x,a2.y,a2.z,a2.w, a3.x,a3.y,a3.z,a3.w};
            #pragma unroll
            for (int i = 0; i < 16; ++i) {
                const int d = dg + i;
                *(unsigned short*)&lds[VT_OFF + ((d * 128 + kk * 2) ^ ((d & 7) << 4))] = f2bf(vals[i]);
            }
        }
        // ---- stage key-mask additive values
        if (tid < 64) {
            const int mv = masks[b * S_LEN + k0 + tid];
            *(float*)&lds[SM_OFF + tid * 4] = mv ? NEG_BIG : 0.0f;
        }
        __syncthreads();

        // ---- QK^T: S[16q][64key], A=Q frag, B=K-tile frag
        f32x4 accs[4];
        #pragma unroll
        for (int g = 0; g < 4; ++g) accs[g] = (f32x4){0.f, 0.f, 0.f, 0.f};
        #pragma unroll
        for (int c = 0; c < 2; ++c) {
            #pragma unroll
            for (int g = 0; g < 4; ++g) {
                const int row = lq + 16 * g;  // key
                bf16x8 bf = *(const bf16x8*)&lds[KT_OFF + ((row * 128 + lk * 16 + c * 64) ^ ((lane & 7) << 4))];
                accs[g] = __builtin_amdgcn_mfma_f32_16x16x32_bf16(qf[c], bf, accs[g], 0, 0, 0);
            }
        }

        // ---- mask + online softmax; C layout: row q = 4*lk + r, col key = lq + 16g
        const bool diag = (k0 + KBLK > q0);
        float smk[4];
        #pragma unroll
        for (int g = 0; g < 4; ++g) smk[g] = *(const float*)&lds[SM_OFF + (lq + 16 * g) * 4];

        #pragma unroll
        for (int r = 0; r < 4; ++r) {
            const int qrow = q0 + w * 16 + 4 * lk + r;
            float sv[4];
            #pragma unroll
            for (int g = 0; g < 4; ++g) {
                float x = accs[g][r] + smk[g];
                if (diag && (k0 + 16 * g + lq > qrow)) x = NEG_BIG;
                sv[g] = x;
            }
            float rowmax = fmaxf(fmaxf(sv[0], sv[1]), fmaxf(sv[2], sv[3]));
            #pragma unroll
            for (int off = 1; off < 16; off <<= 1)
                rowmax = fmaxf(rowmax, __shfl_xor(rowmax, off, 64));
            const float newm = fmaxf(m_r[r], rowmax);
            const float sc = exp2f(m_r[r] - newm);  // -inf first time -> 0
            float p[4];
            float ts = 0.f;
            #pragma unroll
            for (int g = 0; g < 4; ++g) { p[g] = exp2f(sv[g] - newm); ts += p[g]; }
            #pragma unroll
            for (int off = 1; off < 16; off <<= 1)
                ts += __shfl_xor(ts, off, 64);
            l_r[r] = l_r[r] * sc + ts;
            m_r[r] = newm;
            #pragma unroll
            for (int g = 0; g < 4; ++g) acc_o[g][r] *= sc;
            // write P tile (per-wave private region)
            const int prow = 4 * lk + r;
            const int pswz = (prow & 7) << 4;
            #pragma unroll
            for (int g = 0; g < 4; ++g)
                *(unsigned short*)&lds[P_OFF + (w << 11) + ((prow * 128 + (lq + 16 * g) * 2) ^ pswz)] = f2bf(p[g]);
        }
        __syncthreads();  // P visible + lgkm drained before re-read

        // ---- PV: O += P[16q x 64k] * V[64k x 64d]
        #pragma unroll
        for (int c = 0; c < 2; ++c) {
            bf16x8 pa = *(const bf16x8*)&lds[P_OFF + (w << 11) + ((lq * 128 + lk * 16 + c * 64) ^ ((lq & 7) << 4))];
            #pragma unroll
            for (int g = 0; g < 4; ++g) {
                const int d = lq + 16 * g;
                bf16x8 vb = *(const bf16x8*)&lds[VT_OFF + ((d * 128 + lk * 16 + c * 64) ^ ((lane & 7) << 4))];
                acc_o[g] = __builtin_amdgcn_mfma_f32_16x16x32_bf16(pa, vb, acc_o[g], 0, 0, 0);
            }
        }
    }

    // ---- epilogue: normalize; dead-prefix rows (all causal keys masked) -> mean(V)
    const int myL = Lb[b];
    #pragma unroll
    for (int r = 0; r < 4; ++r) {
        const int qrow = q0 + w * 16 + 4 * lk + r;
        float* orow = out + ((size_t)bh * S_LEN + qrow) * HDIM;
        const float inv = 1.0f / l_r[r];
        if (qrow < myL) {
            #pragma unroll
            for (int g = 0; g < 4; ++g) orow[lq + 16 * g] = meanV[bh * HDIM + lq + 16 * g];
        } else {
            #pragma unroll
            for (int g = 0; g < 4; ++g) orow[lq + 16 * g] = acc_o[g][r] * inv;
        }
    }
}

extern "C" void kernel_launch(void* const* d_in, const int* in_sizes, int n_in,
                              void* d_out, int out_size, void* d_ws, size_t ws_size,
                              hipStream_t stream)
{
    const float* Q     = (const float*)d_in[0];
    const float* K     = (const float*)d_in[1];
    const float* V     = (const float*)d_in[2];
    const int*   masks = (const int*)d_in[3];
    float* out = (float*)d_out;

    float* meanV = (float*)d_ws;                          // 32*64 floats
    int*   Lb    = (int*)((char*)d_ws + NHEAD * HDIM * 4); // 4 ints

    firstzero_kernel<<<dim3(NBATCH), dim3(256), 0, stream>>>(masks, Lb);
    meanv_kernel<<<dim3(NHEAD), dim3(256), 0, stream>>>(V, meanV);
    attn_fwd<<<dim3(S_LEN / QBLK, NHEAD), dim3(256), 0, stream>>>(Q, K, V, masks, meanV, Lb, out);
}

// Round 2
// 180.364 us; speedup vs baseline: 1.6239x; 1.6239x over previous
//
#include <hip/hip_runtime.h>

#define S_LEN 2048
#define HDIM  64
#define NHEAD 32
#define NBATCH 4
#define QBLK 64
#define KBLK 64
// fold 1/sqrt(64) and log2(e) into Q so softmax uses exp2
#define QK_SCALE (0.125f * 1.44269504088896341f)

typedef float f32x4 __attribute__((ext_vector_type(4)));
typedef short bf16x8 __attribute__((ext_vector_type(8)));

static __device__ __forceinline__ unsigned int cvt_pk_bf16(float lo, float hi) {
    unsigned int r;
    asm("v_cvt_pk_bf16_f32 %0, %1, %2" : "=v"(r) : "v"(lo), "v"(hi));
    return r;  // low 16 = bf16(lo), high 16 = bf16(hi)
}

// ---------- pre-kernel 1: per-batch first unmasked key + packed mask bits ----------
__global__ void maskprep_kernel(const int* __restrict__ masks,
                                int* __restrict__ Lb,
                                unsigned long long* __restrict__ MB) {
    const int b = blockIdx.x;
    const int t = threadIdx.x;  // 64 threads
    __shared__ int smin;
    if (t == 0) smin = S_LEN;
    __syncthreads();
    int local = S_LEN;
    for (int k = t; k < S_LEN; k += 64) {
        if (masks[b * S_LEN + k] == 0) { local = k; break; }
    }
    atomicMin(&smin, local);
    if (t < 32) {  // pack word t: keys t*64 .. t*64+63; bit set = masked (exclude)
        unsigned long long wbits = 0ull;
        for (int i = 0; i < 64; ++i)
            wbits |= (unsigned long long)(masks[b * S_LEN + t * 64 + i] & 1) << i;
        MB[b * 32 + t] = wbits;
    }
    __syncthreads();
    if (t == 0) Lb[b] = smin;
}

// ---------- pre-kernel 2: per-head mean of V over keys (dead-row output) ----------
__global__ void meanv_kernel(const float* __restrict__ V, float* __restrict__ meanV) {
    const int bh = blockIdx.x;
    const int t = threadIdx.x;
    const int d = t & 63;
    const int part = t >> 6;
    const float* Vb = V + (size_t)bh * S_LEN * HDIM;
    float s = 0.f;
    const int k0 = part * (S_LEN / 4);
    for (int k = k0; k < k0 + S_LEN / 4; ++k) s += Vb[(size_t)k * HDIM + d];
    __shared__ float red[4][64];
    red[part][d] = s;
    __syncthreads();
    if (t < 64) {
        float tot = red[0][t] + red[1][t] + red[2][t] + red[3][t];
        meanV[bh * HDIM + t] = tot * (1.0f / (float)S_LEN);
    }
}

// ---------- main flash-attention kernel ----------
// LDS: Kbuf0[8K] Vbuf0[8K] Kbuf1[8K] Vbuf1[8K] P[4 waves][2K] = 40960 B
#define P_OFF 32768
#define LDSB  40960

__global__ __launch_bounds__(256) void attn_fwd(
    const float* __restrict__ Q, const float* __restrict__ K,
    const float* __restrict__ V, const float* __restrict__ meanV,
    const int* __restrict__ Lb, const unsigned long long* __restrict__ MB,
    float* __restrict__ out)
{
    __shared__ __align__(16) char lds[LDSB];
    const int tid  = threadIdx.x;
    const int lane = tid & 63;
    const int w    = tid >> 6;          // wave 0..3
    const int lq   = lane & 15;         // q (and d / key-row) sublane
    const int lk   = lane >> 4;         // k-chunk sublane

    // XCD-chunked remap: 8 XCDs x 128 blocks; each XCD gets 4 heads (K/V L2-local),
    // big q-tiles dispatched first for balance.
    const int bid  = blockIdx.x;
    const int nbid = (bid & 7) * 128 + (bid >> 3);
    const int bh   = nbid >> 5;
    const int qb   = 31 - (nbid & 31);  // descending work order
    const int q0   = qb * QBLK;
    const int b    = bh & (NBATCH - 1);
    const int nt   = qb + 1;

    const size_t ho = (size_t)bh * S_LEN * HDIM;
    const float* Qh = Q + ho;
    const float* Kh = K + ho;
    const float* Vh = V + ho;

    // ---- Q fragments (B-operand of swapped QK^T: col=q=lane%16, k=8*lk+j)
    bf16x8 qf[2];
    {
        const float* qrow = Qh + (size_t)(q0 + w * 16 + lq) * HDIM;
        #pragma unroll
        for (int c = 0; c < 2; ++c) {
            const int d0 = lk * 8 + c * 32;
            float4 f0 = *(const float4*)(qrow + d0);
            float4 f1 = *(const float4*)(qrow + d0 + 4);
            int4 qi;
            qi.x = cvt_pk_bf16(f0.x * QK_SCALE, f0.y * QK_SCALE);
            qi.y = cvt_pk_bf16(f0.z * QK_SCALE, f0.w * QK_SCALE);
            qi.z = cvt_pk_bf16(f1.x * QK_SCALE, f1.y * QK_SCALE);
            qi.w = cvt_pk_bf16(f1.z * QK_SCALE, f1.w * QK_SCALE);
            qf[c] = *(bf16x8*)&qi;
        }
    }

    // ---- staging coordinates
    const int kr = tid >> 2;             // K: key row 0..63
    const int kc = (tid & 3) << 4;       // K: f32 col base
    const float* Kp = Kh + (size_t)kr * HDIM + kc;
    const int vd = lane;                 // V: d column 0..63
    const int vk = w * 16;               // V: key base (16 keys per wave)
    const float* Vp = Vh + (size_t)vk * HDIM + vd;

    float4 ka0, ka1, ka2, ka3;
    float va[16];

    auto LOADKV = [&](int kk0) {
        const float4* kp = (const float4*)(Kp + (size_t)kk0 * HDIM);
        ka0 = kp[0]; ka1 = kp[1]; ka2 = kp[2]; ka3 = kp[3];
        const float* vp = Vp + (size_t)kk0 * HDIM;
        #pragma unroll
        for (int i = 0; i < 16; ++i) va[i] = vp[i * HDIM];  // coalesced 256B/instr
    };
    auto WRITEKV = [&](int bufbase) {
        int4 kv0, kv1;
        kv0.x = cvt_pk_bf16(ka0.x, ka0.y); kv0.y = cvt_pk_bf16(ka0.z, ka0.w);
        kv0.z = cvt_pk_bf16(ka1.x, ka1.y); kv0.w = cvt_pk_bf16(ka1.z, ka1.w);
        kv1.x = cvt_pk_bf16(ka2.x, ka2.y); kv1.y = cvt_pk_bf16(ka2.z, ka2.w);
        kv1.z = cvt_pk_bf16(ka3.x, ka3.y); kv1.w = cvt_pk_bf16(ka3.z, ka3.w);
        const int kswz = (kr & 7) << 4;
        *(int4*)&lds[bufbase + ((kr * 128 + kc * 2)      ^ kswz)] = kv0;
        *(int4*)&lds[bufbase + ((kr * 128 + kc * 2 + 16) ^ kswz)] = kv1;
        int4 vv0, vv1;
        vv0.x = cvt_pk_bf16(va[0],  va[1]);  vv0.y = cvt_pk_bf16(va[2],  va[3]);
        vv0.z = cvt_pk_bf16(va[4],  va[5]);  vv0.w = cvt_pk_bf16(va[6],  va[7]);
        vv1.x = cvt_pk_bf16(va[8],  va[9]);  vv1.y = cvt_pk_bf16(va[10], va[11]);
        vv1.z = cvt_pk_bf16(va[12], va[13]); vv1.w = cvt_pk_bf16(va[14], va[15]);
        const int vswz = (vd & 7) << 4;
        *(int4*)&lds[bufbase + 8192 + ((vd * 128 + vk * 2)      ^ vswz)] = vv0;
        *(int4*)&lds[bufbase + 8192 + ((vd * 128 + vk * 2 + 16) ^ vswz)] = vv1;
    };

    f32x4 acc[4];
    #pragma unroll
    for (int g = 0; g < 4; ++g) acc[g] = (f32x4){0.f, 0.f, 0.f, 0.f};
    float m_r = -__builtin_inff();
    float l_r = 0.f;

    const int swz = (lq & 7) << 4;
    const int pbase = P_OFF + (w << 11);
    const int wq = w * 16 + lq;

    // prologue: stage tile 0
    LOADKV(0);
    WRITEKV(0);
    __syncthreads();

    for (int t = 0; t < nt; ++t) {
        const int cur = t & 1;
        const int kb  = cur << 14;       // K buf base
        const bool pre = (t + 1) < nt;
        if (pre) LOADKV((t + 1) * KBLK);  // issue early; writes after PV (T14)

        // ---- QK^T swapped: S^T[key][q] = mfma(A=K, B=Q)
        f32x4 sacc[4];
        #pragma unroll
        for (int g = 0; g < 4; ++g) sacc[g] = (f32x4){0.f, 0.f, 0.f, 0.f};
        #pragma unroll
        for (int c = 0; c < 2; ++c) {
            #pragma unroll
            for (int g = 0; g < 4; ++g) {
                bf16x8 kf = *(const bf16x8*)&lds[kb + (((16 * g + lq) * 128 + 16 * lk + 64 * c) ^ swz)];
                sacc[g] = __builtin_amdgcn_mfma_f32_16x16x32_bf16(kf, qf[c], sacc[g], 0, 0, 0);
            }
        }

        // ---- lane-local softmax: lane owns q=lq, 16 keys (16g+4lk+r)
        const unsigned long long mb = MB[(b << 5) + t];
        const bool diag = (t == nt - 1);

        float mloc = sacc[0][0];
        #pragma unroll
        for (int g = 0; g < 4; ++g)
            #pragma unroll
            for (int r = 0; r < 4; ++r) mloc = fmaxf(mloc, sacc[g][r]);
        mloc = fmaxf(mloc, __shfl_xor(mloc, 16, 64));
        mloc = fmaxf(mloc, __shfl_xor(mloc, 32, 64));
        const float newm = fmaxf(m_r, mloc);
        const float sc = exp2f(m_r - newm);  // first tile: exp2(-inf)=0

        float ls = 0.f;
        #pragma unroll
        for (int g = 0; g < 4; ++g) {
            const unsigned int nib = (unsigned int)(mb >> (16 * g + 4 * lk)) & 0xFu;
            #pragma unroll
            for (int r = 0; r < 4; ++r) {
                const int kidx = 16 * g + 4 * lk + r;
                float e = exp2f(sacc[g][r] - newm);
                const bool kill = ((nib >> r) & 1u) || (diag && kidx > wq);
                e = kill ? 0.f : e;
                sacc[g][r] = e;  // reuse as P
                ls += e;
            }
        }
        ls += __shfl_xor(ls, 16, 64);
        ls += __shfl_xor(ls, 32, 64);
        l_r = l_r * sc + ls;
        m_r = newm;

        // broadcast rescale factor to PV-acc layout (row q = 4*lk+r)
        float scb[4];
        #pragma unroll
        for (int r = 0; r < 4; ++r) scb[r] = __shfl(sc, 4 * lk + r, 64);
        #pragma unroll
        for (int g = 0; g < 4; ++g)
            #pragma unroll
            for (int r = 0; r < 4; ++r) acc[g][r] *= scb[r];

        // ---- P write (wave-private region, vectorized b64, swizzled)
        #pragma unroll
        for (int g = 0; g < 4; ++g) {
            uint2 pw;
            pw.x = cvt_pk_bf16(sacc[g][0], sacc[g][1]);
            pw.y = cvt_pk_bf16(sacc[g][2], sacc[g][3]);
            *(uint2*)&lds[pbase + ((lq * 128 + 32 * g + 8 * lk) ^ swz)] = pw;
        }

        // ---- PV: O[q][d] += P[q][k] V[k][d]   (P wave-private: no barrier needed)
        #pragma unroll
        for (int c = 0; c < 2; ++c) {
            bf16x8 pa = *(const bf16x8*)&lds[pbase + ((lq * 128 + 16 * lk + 64 * c) ^ swz)];
            #pragma unroll
            for (int g = 0; g < 4; ++g) {
                bf16x8 vb = *(const bf16x8*)&lds[kb + 8192 + (((lq + 16 * g) * 128 + 16 * lk + 64 * c) ^ swz)];
                acc[g] = __builtin_amdgcn_mfma_f32_16x16x32_bf16(pa, vb, acc[g], 0, 0, 0);
            }
        }

        // ---- write next tile into other buffer; single barrier per tile
        if (pre) WRITEKV((cur ^ 1) << 14);
        __syncthreads();
    }

    // ---- epilogue: normalize; dead-prefix rows (q < Lb) -> mean(V)
    const int myL = Lb[b];
    const float linv_s = 1.0f / l_r;  // per q=lq (inf only for dead rows; overridden)
    float linv[4];
    #pragma unroll
    for (int r = 0; r < 4; ++r) linv[r] = __shfl(linv_s, 4 * lk + r, 64);
    #pragma unroll
    for (int r = 0; r < 4; ++r) {
        const int qrow = q0 + w * 16 + 4 * lk + r;
        float* orow = out + ho + (size_t)qrow * HDIM;
        if (qrow < myL) {
            #pragma unroll
            for (int g = 0; g < 4; ++g) orow[lq + 16 * g] = meanV[bh * HDIM + lq + 16 * g];
        } else {
            #pragma unroll
            for (int g = 0; g < 4; ++g) orow[lq + 16 * g] = acc[g][r] * linv[r];
        }
    }
}

extern "C" void kernel_launch(void* const* d_in, const int* in_sizes, int n_in,
                              void* d_out, int out_size, void* d_ws, size_t ws_size,
                              hipStream_t stream)
{
    const float* Q     = (const float*)d_in[0];
    const float* K     = (const float*)d_in[1];
    const float* V     = (const float*)d_in[2];
    const int*   masks = (const int*)d_in[3];
    float* out = (float*)d_out;

    float* meanV = (float*)d_ws;                                     // 32*64 f32 = 8192 B
    int*   Lb    = (int*)((char*)d_ws + 8192);                       // 16 B
    unsigned long long* MB = (unsigned long long*)((char*)d_ws + 8208); // 4*32*8 = 1024 B

    maskprep_kernel<<<dim3(NBATCH), dim3(64), 0, stream>>>(masks, Lb, MB);
    meanv_kernel<<<dim3(NHEAD), dim3(256), 0, stream>>>(V, meanV);
    attn_fwd<<<dim3(1024), dim3(256), 0, stream>>>(Q, K, V, meanV, Lb, MB, out);
}

// Round 4
// 155.534 us; speedup vs baseline: 1.8831x; 1.1596x over previous
//
#include <hip/hip_runtime.h>
#include <stdint.h>

#define S_LEN 2048
#define HDIM  64
#define NHEAD 32
#define NBATCH 4
#define QBLK 64
#define KBLK 64
// fold 1/sqrt(64) and log2(e) into Q so softmax uses exp2
#define QK_SCALE (0.125f * 1.44269504088896341f)
#define DEFER_THR 8.0f

typedef float f32x4 __attribute__((ext_vector_type(4)));
typedef short bf16x8 __attribute__((ext_vector_type(8)));

// ---- workspace layout (bytes) ----
#define WS_MEANV 0
#define WS_MB    8192
#define WS_KBF   16384
#define KVBYTES  (NHEAD * 32 * 8192)          // 8 MiB per tensor image
#define WS_VTBF  (WS_KBF + (size_t)KVBYTES)
#define WS_NEED_PRE (WS_VTBF + (size_t)KVBYTES)

static __device__ __forceinline__ unsigned int cvt_pk_bf16(float lo, float hi) {
    unsigned int r;
    asm("v_cvt_pk_bf16_f32 %0, %1, %2" : "=v"(r) : "v"(lo), "v"(hi));
    return r;  // low16 = bf16(lo), high16 = bf16(hi)
}

static __device__ __forceinline__ void load_lds16(const void* g, void* l) {
    __builtin_amdgcn_global_load_lds(
        (const __attribute__((address_space(1))) uint32_t*)g,
        (__attribute__((address_space(3))) uint32_t*)l, 16, 0, 0);
}

// ---------- pre-kernel: packed mask bits via ballot ----------
__global__ void maskprep_kernel(const int* __restrict__ masks,
                                unsigned long long* __restrict__ MB) {
    const int b = blockIdx.x;
    const int lane = threadIdx.x & 63;
    const int w = threadIdx.x >> 6;
    #pragma unroll
    for (int i = 0; i < 8; ++i) {
        const int word = i * 4 + w;
        const int m = masks[b * S_LEN + word * 64 + lane];
        const unsigned long long bits = __ballot(m != 0);
        if (lane == 0) MB[b * 32 + word] = bits;
    }
}

// ---------- fallback meanV (used only when ws too small for PRE) ----------
__global__ void meanv_atomic_kernel(const float* __restrict__ V, float* __restrict__ meanV) {
    const int bh = blockIdx.x >> 3, part = blockIdx.x & 7;
    const int t = threadIdx.x, d = t & 63, sub = t >> 6;
    const float* Vb = V + (size_t)bh * S_LEN * HDIM;
    float s = 0.f;
    const int k0 = part * 256 + sub * 64;
    for (int k = k0; k < k0 + 64; ++k) s += Vb[(size_t)k * HDIM + d];
    __shared__ float red[4][64];
    red[sub][d] = s;
    __syncthreads();
    if (t < 64) {
        float tot = red[0][t] + red[1][t] + red[2][t] + red[3][t];
        atomicAdd(&meanV[bh * HDIM + t], tot * (1.0f / (float)S_LEN));
    }
}

// ---------- pre-kernel: K & V^T -> bf16 tile-swizzled global images + meanV ----------
// Image per (bh, tile): 8192 B, laid out EXACTLY as the attn kernel's LDS tile,
// so a linear global_load_lds copy reproduces it.
__global__ __launch_bounds__(256) void cvt_kernel(
    const float* __restrict__ K, const float* __restrict__ V,
    uint8_t* __restrict__ Kbf, uint8_t* __restrict__ Vtbf,
    float* __restrict__ meanV)
{
    const int bh = blockIdx.x >> 5, t = blockIdx.x & 31;
    const int tid = threadIdx.x, lane = tid & 63, w = tid >> 6;
    const size_t ho = (size_t)bh * S_LEN * HDIM;
    const size_t img = ((size_t)bh * 32 + t) * 8192;

    // K: [key][d] bf16, swizzled rows
    {
        const int kr = tid >> 2;           // key row 0..63
        const int kc = (tid & 3) << 4;     // f32 col base
        const float4* kp = (const float4*)(K + ho + (size_t)(t * 64 + kr) * HDIM + kc);
        float4 a0 = kp[0], a1 = kp[1], a2 = kp[2], a3 = kp[3];
        int4 kv0, kv1;
        kv0.x = cvt_pk_bf16(a0.x, a0.y); kv0.y = cvt_pk_bf16(a0.z, a0.w);
        kv0.z = cvt_pk_bf16(a1.x, a1.y); kv0.w = cvt_pk_bf16(a1.z, a1.w);
        kv1.x = cvt_pk_bf16(a2.x, a2.y); kv1.y = cvt_pk_bf16(a2.z, a2.w);
        kv1.z = cvt_pk_bf16(a3.x, a3.y); kv1.w = cvt_pk_bf16(a3.z, a3.w);
        const int swz = (kr & 7) << 4;
        *(int4*)&Kbf[img + ((kr * 128 + kc * 2)      ^ swz)] = kv0;
        *(int4*)&Kbf[img + ((kr * 128 + kc * 2 + 16) ^ swz)] = kv1;
    }
    // V^T: [d][key] bf16, swizzled rows; also accumulate meanV
    {
        const int vd = lane;               // d 0..63
        const int vk = w * 16;             // key base
        const float* vp = V + ho + (size_t)(t * 64 + vk) * HDIM + vd;
        float va[16];
        float psum = 0.f;
        #pragma unroll
        for (int i = 0; i < 16; ++i) { va[i] = vp[(size_t)i * HDIM]; psum += va[i]; }
        int4 vv0, vv1;
        vv0.x = cvt_pk_bf16(va[0],  va[1]);  vv0.y = cvt_pk_bf16(va[2],  va[3]);
        vv0.z = cvt_pk_bf16(va[4],  va[5]);  vv0.w = cvt_pk_bf16(va[6],  va[7]);
        vv1.x = cvt_pk_bf16(va[8],  va[9]);  vv1.y = cvt_pk_bf16(va[10], va[11]);
        vv1.z = cvt_pk_bf16(va[12], va[13]); vv1.w = cvt_pk_bf16(va[14], va[15]);
        const int swz = (vd & 7) << 4;
        *(int4*)&Vtbf[img + ((vd * 128 + vk * 2)      ^ swz)] = vv0;
        *(int4*)&Vtbf[img + ((vd * 128 + vk * 2 + 16) ^ swz)] = vv1;
        __shared__ float red[4][64];
        red[w][vd] = psum;
        __syncthreads();
        if (tid < 64) {
            float tot = red[0][tid] + red[1][tid] + red[2][tid] + red[3][tid];
            atomicAdd(&meanV[bh * HDIM + tid], tot * (1.0f / (float)S_LEN));
        }
    }
}

// ---------- main flash-attention kernel ----------
// LDS: buf0{K 8K, V 8K} buf1{K 8K, V 8K} P[4 waves][2K] = 40960 B
#define P_OFF 32768
#define LDSB  40960

template<bool PRE>
__global__ __launch_bounds__(256) void attn_fwd(
    const float* __restrict__ Q, const float* __restrict__ K,
    const float* __restrict__ V, const float* __restrict__ meanV,
    const unsigned long long* __restrict__ MB,
    const uint8_t* __restrict__ Kbf, const uint8_t* __restrict__ Vtbf,
    float* __restrict__ out)
{
    __shared__ __align__(16) char lds[LDSB];
    const int tid  = threadIdx.x;
    const int lane = tid & 63;
    const int w    = tid >> 6;
    const int lq   = lane & 15;
    const int lk   = lane >> 4;

    // XCD-chunked remap: 8 XCDs x 64 blocks; 4 heads per XCD (KV L2-local).
    const int bid  = blockIdx.x;
    const int nbid = (bid & 7) * 64 + (bid >> 3);
    const int bh   = nbid >> 4;         // head 0..31
    const int j    = nbid & 15;         // pair index: q-tiles j and 31-j (33 tiles total)
    const int b    = bh & (NBATCH - 1);

    const size_t ho = (size_t)bh * S_LEN * HDIM;
    const float* Qh = Q + ho;
    const float* Kh = K + ho;
    const float* Vh = V + ho;
    const uint8_t* kimg = Kbf  + (size_t)bh * 32 * 8192;
    const uint8_t* vimg = Vtbf + (size_t)bh * 32 * 8192;

    // fallback staging coords
    const int kr = tid >> 2;
    const int kc = (tid & 3) << 4;
    const int vd = lane;
    const int vk = w * 16;
    const float* Kp = Kh + (size_t)kr * HDIM + kc;
    const float* Vp = Vh + (size_t)vk * HDIM + vd;
    float4 ka0, ka1, ka2, ka3;
    float va[16];

    auto STAGE = [&](int t, int bufbase) {  // PRE: 4 async 16B/lane copies
        const uint8_t* gk = kimg + (size_t)t * 8192 + w * 2048 + lane * 16;
        const uint8_t* gv = vimg + (size_t)t * 8192 + w * 2048 + lane * 16;
        load_lds16(gk,        &lds[bufbase + w * 2048]);
        load_lds16(gk + 1024, &lds[bufbase + w * 2048 + 1024]);
        load_lds16(gv,        &lds[bufbase + 8192 + w * 2048]);
        load_lds16(gv + 1024, &lds[bufbase + 8192 + w * 2048 + 1024]);
    };
    auto LOADKV = [&](int kk0) {
        const float4* kp = (const float4*)(Kp + (size_t)kk0 * HDIM);
        ka0 = kp[0]; ka1 = kp[1]; ka2 = kp[2]; ka3 = kp[3];
        const float* vp = Vp + (size_t)kk0 * HDIM;
        #pragma unroll
        for (int i = 0; i < 16; ++i) va[i] = vp[(size_t)i * HDIM];
    };
    auto WRITEKV = [&](int bufbase) {
        int4 kv0, kv1;
        kv0.x = cvt_pk_bf16(ka0.x, ka0.y); kv0.y = cvt_pk_bf16(ka0.z, ka0.w);
        kv0.z = cvt_pk_bf16(ka1.x, ka1.y); kv0.w = cvt_pk_bf16(ka1.z, ka1.w);
        kv1.x = cvt_pk_bf16(ka2.x, ka2.y); kv1.y = cvt_pk_bf16(ka2.z, ka2.w);
        kv1.z = cvt_pk_bf16(ka3.x, ka3.y); kv1.w = cvt_pk_bf16(ka3.z, ka3.w);
        const int kswz = (kr & 7) << 4;
        *(int4*)&lds[bufbase + ((kr * 128 + kc * 2)      ^ kswz)] = kv0;
        *(int4*)&lds[bufbase + ((kr * 128 + kc * 2 + 16) ^ kswz)] = kv1;
        int4 vv0, vv1;
        vv0.x = cvt_pk_bf16(va[0],  va[1]);  vv0.y = cvt_pk_bf16(va[2],  va[3]);
        vv0.z = cvt_pk_bf16(va[4],  va[5]);  vv0.w = cvt_pk_bf16(va[6],  va[7]);
        vv1.x = cvt_pk_bf16(va[8],  va[9]);  vv1.y = cvt_pk_bf16(va[10], va[11]);
        vv1.z = cvt_pk_bf16(va[12], va[13]); vv1.w = cvt_pk_bf16(va[14], va[15]);
        const int vswz = (vd & 7) << 4;
        *(int4*)&lds[bufbase + 8192 + ((vd * 128 + vk * 2)      ^ vswz)] = vv0;
        *(int4*)&lds[bufbase + 8192 + ((vd * 128 + vk * 2 + 16) ^ vswz)] = vv1;
    };

    const int swz = (lq & 7) << 4;
    const int pbase = P_OFF + (w << 11);
    const int wq = w * 16 + lq;

    #pragma unroll 1
    for (int pass = 0; pass < 2; ++pass) {
        const int qb = pass ? (31 - j) : j;
        const int q0 = qb * QBLK;
        const int nt = qb + 1;

        // Q fragments (B-operand of swapped QK^T)
        bf16x8 qf[2];
        {
            const float* qrow = Qh + (size_t)(q0 + w * 16 + lq) * HDIM;
            #pragma unroll
            for (int c = 0; c < 2; ++c) {
                const int d0 = lk * 8 + c * 32;
                float4 f0 = *(const float4*)(qrow + d0);
                float4 f1 = *(const float4*)(qrow + d0 + 4);
                int4 qi;
                qi.x = cvt_pk_bf16(f0.x * QK_SCALE, f0.y * QK_SCALE);
                qi.y = cvt_pk_bf16(f0.z * QK_SCALE, f0.w * QK_SCALE);
                qi.z = cvt_pk_bf16(f1.x * QK_SCALE, f1.y * QK_SCALE);
                qi.w = cvt_pk_bf16(f1.z * QK_SCALE, f1.w * QK_SCALE);
                qf[c] = *(bf16x8*)&qi;
            }
        }

        f32x4 acc[4];
        #pragma unroll
        for (int g = 0; g < 4; ++g) acc[g] = (f32x4){0.f, 0.f, 0.f, 0.f};
        float m_r = -__builtin_inff();
        float l_r = 0.f;

        // prologue: stage tile 0 into buf0 (previous pass's barrier protects LDS)
        if constexpr (PRE) STAGE(0, 0);
        else { LOADKV(0); WRITEKV(0); }
        __syncthreads();

        for (int t = 0; t < nt; ++t) {
            const int cur = t & 1;
            const int kb  = cur << 14;
            const bool pre = (t + 1) < nt;
            if constexpr (PRE) { if (pre) STAGE(t + 1, (cur ^ 1) << 14); }
            else               { if (pre) LOADKV((t + 1) * KBLK); }

            // QK^T swapped: S^T = mfma(A=K, B=Q); lane owns q=lq, keys 16g+4lk+r
            f32x4 sacc[4];
            #pragma unroll
            for (int g = 0; g < 4; ++g) sacc[g] = (f32x4){0.f, 0.f, 0.f, 0.f};
            __builtin_amdgcn_s_setprio(1);
            #pragma unroll
            for (int c = 0; c < 2; ++c) {
                #pragma unroll
                for (int g = 0; g < 4; ++g) {
                    bf16x8 kf = *(const bf16x8*)&lds[kb + (((16 * g + lq) * 128 + 16 * lk + 64 * c) ^ swz)];
                    sacc[g] = __builtin_amdgcn_mfma_f32_16x16x32_bf16(kf, qf[c], sacc[g], 0, 0, 0);
                }
            }
            __builtin_amdgcn_s_setprio(0);

            const unsigned long long mb = MB[(b << 5) + t];
            const bool diag = (t == nt - 1);

            float mloc = sacc[0][0];
            #pragma unroll
            for (int g = 0; g < 4; ++g)
                #pragma unroll
                for (int r = 0; r < 4; ++r) mloc = fmaxf(mloc, sacc[g][r]);
            mloc = fmaxf(mloc, __shfl_xor(mloc, 16, 64));
            mloc = fmaxf(mloc, __shfl_xor(mloc, 32, 64));

            // defer-max (T13): only rescale when the running max grows materially
            if (!__all(mloc - m_r <= DEFER_THR)) {
                const float newm = fmaxf(m_r, mloc);
                const float sc = exp2f(m_r - newm);  // first tile: exp2(-inf)=0
                l_r *= sc;
                m_r = newm;
                float scb[4];
                #pragma unroll
                for (int r = 0; r < 4; ++r) scb[r] = __shfl(sc, 4 * lk + r, 64);
                #pragma unroll
                for (int g = 0; g < 4; ++g)
                    #pragma unroll
                    for (int r = 0; r < 4; ++r) acc[g][r] *= scb[r];
            }

            float ls = 0.f;
            #pragma unroll
            for (int g = 0; g < 4; ++g) {
                const unsigned int nib = (unsigned int)(mb >> (16 * g + 4 * lk)) & 0xFu;
                #pragma unroll
                for (int r = 0; r < 4; ++r) {
                    const int kidx = 16 * g + 4 * lk + r;
                    float e = exp2f(sacc[g][r] - m_r);
                    const bool kill = ((nib >> r) & 1u) || (diag && kidx > wq);
                    e = kill ? 0.f : e;
                    sacc[g][r] = e;
                    ls += e;
                }
            }
            ls += __shfl_xor(ls, 16, 64);
            ls += __shfl_xor(ls, 32, 64);
            l_r += ls;

            // P write (wave-private, vectorized, swizzled)
            #pragma unroll
            for (int g = 0; g < 4; ++g) {
                uint2 pw;
                pw.x = cvt_pk_bf16(sacc[g][0], sacc[g][1]);
                pw.y = cvt_pk_bf16(sacc[g][2], sacc[g][3]);
                *(uint2*)&lds[pbase + ((lq * 128 + 32 * g + 8 * lk) ^ swz)] = pw;
            }

            // PV
            __builtin_amdgcn_s_setprio(1);
            #pragma unroll
            for (int c = 0; c < 2; ++c) {
                bf16x8 pa = *(const bf16x8*)&lds[pbase + ((lq * 128 + 16 * lk + 64 * c) ^ swz)];
                #pragma unroll
                for (int g = 0; g < 4; ++g) {
                    bf16x8 vb = *(const bf16x8*)&lds[kb + 8192 + (((lq + 16 * g) * 128 + 16 * lk + 64 * c) ^ swz)];
                    acc[g] = __builtin_amdgcn_mfma_f32_16x16x32_bf16(pa, vb, acc[g], 0, 0, 0);
                }
            }
            __builtin_amdgcn_s_setprio(0);

            if constexpr (!PRE) { if (pre) WRITEKV((cur ^ 1) << 14); }
            __syncthreads();
        }

        // epilogue: dead rows have l == 0 exactly (all keys killed) -> full-mean(V)
        float lr_b[4];
        #pragma unroll
        for (int r = 0; r < 4; ++r) lr_b[r] = __shfl(l_r, 4 * lk + r, 64);
        #pragma unroll
        for (int r = 0; r < 4; ++r) {
            const int qrow = q0 + w * 16 + 4 * lk + r;
            float* orow = out + ho + (size_t)qrow * HDIM;
            if (lr_b[r] == 0.f) {
                #pragma unroll
                for (int g = 0; g < 4; ++g) orow[lq + 16 * g] = meanV[bh * HDIM + lq + 16 * g];
            } else {
                const float inv = 1.0f / lr_b[r];
                #pragma unroll
                for (int g = 0; g < 4; ++g) orow[lq + 16 * g] = acc[g][r] * inv;
            }
        }
    }
}

extern "C" void kernel_launch(void* const* d_in, const int* in_sizes, int n_in,
                              void* d_out, int out_size, void* d_ws, size_t ws_size,
                              hipStream_t stream)
{
    const float* Q     = (const float*)d_in[0];
    const float* K     = (const float*)d_in[1];
    const float* V     = (const float*)d_in[2];
    const int*   masks = (const int*)d_in[3];
    float* out = (float*)d_out;

    char* ws = (char*)d_ws;
    float* meanV = (float*)(ws + WS_MEANV);
    unsigned long long* MB = (unsigned long long*)(ws + WS_MB);

    hipMemsetAsync(meanV, 0, NHEAD * HDIM * sizeof(float), stream);
    maskprep_kernel<<<dim3(NBATCH), dim3(256), 0, stream>>>(masks, MB);

    if (ws_size >= WS_NEED_PRE) {
        uint8_t* Kbf  = (uint8_t*)(ws + WS_KBF);
        uint8_t* Vtbf = (uint8_t*)(ws + WS_VTBF);
        cvt_kernel<<<dim3(NHEAD * 32), dim3(256), 0, stream>>>(K, V, Kbf, Vtbf, meanV);
        attn_fwd<true><<<dim3(512), dim3(256), 0, stream>>>(Q, K, V, meanV, MB, Kbf, Vtbf, out);
    } else {
        meanv_atomic_kernel<<<dim3(256), dim3(256), 0, stream>>>(V, meanV);
        attn_fwd<false><<<dim3(512), dim3(256), 0, stream>>>(Q, K, V, meanV, MB, nullptr, nullptr, out);
    }
}

// Round 5
// 145.810 us; speedup vs baseline: 2.0087x; 1.0667x over previous
//
#include <hip/hip_runtime.h>
#include <stdint.h>

#define S_LEN 2048
#define HDIM  64
#define NHEAD 32
#define NBATCH 4
// fold 1/sqrt(64) and log2(e) into Q so softmax uses exp2
#define QK_SCALE (0.125f * 1.44269504088896341f)
#define DEFER_THR 8.0f
#define NEG_BIG (-1e30f)

typedef float f32x4 __attribute__((ext_vector_type(4)));
typedef short bf16x8 __attribute__((ext_vector_type(8)));

// ---- workspace layout (bytes) ----
#define WS_MB    0                         // 4*32 u64 mask words   (1 KiB)
#define WS_MVP   1024                      // meanV partials bf16 [32][32][64] (128 KiB)
#define WS_KBF   132096                    // K bf16 images, 8 MiB
#define KVB      (NHEAD * 32 * 8192)
#define WS_VTBF  (WS_KBF + (size_t)KVB)    // V^T bf16 images, 8 MiB

static __device__ __forceinline__ unsigned int cvt_pk_bf16(float lo, float hi) {
    unsigned int r;
    asm("v_cvt_pk_bf16_f32 %0, %1, %2" : "=v"(r) : "v"(lo), "v"(hi));
    return r;  // low16 = bf16(lo), high16 = bf16(hi)
}
static __device__ __forceinline__ float bf2f(unsigned short u) {
    return __uint_as_float((unsigned int)u << 16);
}
static __device__ __forceinline__ void load_lds16(const void* g, void* l) {
    __builtin_amdgcn_global_load_lds(
        (const __attribute__((address_space(1))) uint32_t*)g,
        (__attribute__((address_space(3))) uint32_t*)l, 16, 0, 0);
}

// ---------- pre-kernel: K & V^T -> bf16 tile-swizzled images + meanV partials + mask words ----------
__global__ __launch_bounds__(256) void cvt_kernel(
    const float* __restrict__ K, const float* __restrict__ V,
    const int* __restrict__ masks,
    uint8_t* __restrict__ Kbf, uint8_t* __restrict__ Vtbf,
    unsigned short* __restrict__ mvp, unsigned long long* __restrict__ MB)
{
    // XCD-matched decode: head bh lives on XCD bh>>2 (same as attn kernel)
    const int bid = blockIdx.x;
    const int xcd = bid & 7, rem = bid >> 3;
    const int bh  = xcd * 4 + (rem >> 5);
    const int t   = rem & 31;
    const int tid = threadIdx.x, lane = tid & 63, w = tid >> 6;
    const size_t ho  = (size_t)bh * S_LEN * HDIM;
    const size_t img = ((size_t)bh * 32 + t) * 8192;

    // K image: [key][d] bf16, row-swizzled
    {
        const int kr = tid >> 2;           // key row 0..63
        const int kc = (tid & 3) << 4;     // f32 col base
        const float4* kp = (const float4*)(K + ho + (size_t)(t * 64 + kr) * HDIM + kc);
        float4 a0 = kp[0], a1 = kp[1], a2 = kp[2], a3 = kp[3];
        int4 kv0, kv1;
        kv0.x = cvt_pk_bf16(a0.x, a0.y); kv0.y = cvt_pk_bf16(a0.z, a0.w);
        kv0.z = cvt_pk_bf16(a1.x, a1.y); kv0.w = cvt_pk_bf16(a1.z, a1.w);
        kv1.x = cvt_pk_bf16(a2.x, a2.y); kv1.y = cvt_pk_bf16(a2.z, a2.w);
        kv1.z = cvt_pk_bf16(a3.x, a3.y); kv1.w = cvt_pk_bf16(a3.z, a3.w);
        const int swz = (kr & 7) << 4;
        *(int4*)&Kbf[img + ((kr * 128 + kc * 2)      ^ swz)] = kv0;
        *(int4*)&Kbf[img + ((kr * 128 + kc * 2 + 16) ^ swz)] = kv1;
    }
    // V^T image: [d][key] bf16, row-swizzled; meanV partial
    {
        const int vd = lane;               // d 0..63
        const int vk = w * 16;             // key base
        const float* vp = V + ho + (size_t)(t * 64 + vk) * HDIM + vd;
        float va[16];
        float psum = 0.f;
        #pragma unroll
        for (int i = 0; i < 16; ++i) { va[i] = vp[(size_t)i * HDIM]; psum += va[i]; }
        int4 vv0, vv1;
        vv0.x = cvt_pk_bf16(va[0],  va[1]);  vv0.y = cvt_pk_bf16(va[2],  va[3]);
        vv0.z = cvt_pk_bf16(va[4],  va[5]);  vv0.w = cvt_pk_bf16(va[6],  va[7]);
        vv1.x = cvt_pk_bf16(va[8],  va[9]);  vv1.y = cvt_pk_bf16(va[10], va[11]);
        vv1.z = cvt_pk_bf16(va[12], va[13]); vv1.w = cvt_pk_bf16(va[14], va[15]);
        const int swz = (vd & 7) << 4;
        *(int4*)&Vtbf[img + ((vd * 128 + vk * 2)      ^ swz)] = vv0;
        *(int4*)&Vtbf[img + ((vd * 128 + vk * 2 + 16) ^ swz)] = vv1;
        __shared__ float red[4][64];
        red[w][vd] = psum;
        __syncthreads();
        if (tid < 64) {
            float tot = red[0][tid] + red[1][tid] + red[2][tid] + red[3][tid];
            mvp[(bh * 32 + t) * 64 + tid] = (unsigned short)(cvt_pk_bf16(tot * (1.0f / (float)S_LEN), 0.f) & 0xFFFF);
        }
    }
    // packed mask word for (batch=bh, 64-key tile t), only heads 0..3 do it
    if (bh < NBATCH && tid < 64) {
        const int m = masks[bh * S_LEN + t * 64 + lane];
        const unsigned long long bits = __ballot(m != 0);
        if (lane == 0) MB[bh * 32 + t] = bits;
    }
}

// ---------- main flash-attention kernel ----------
// Dynamic LDS 81920 B:
//   [0,32768)  buf0: K imgs (2x8K) @0, V^T imgs (2x8K) @16384
//   [32768,65536) buf1
//   [65536,81920) P per wave: 16q x 128k bf16, 4 KiB each
__global__ __launch_bounds__(256) void attn_fwd(
    const float* __restrict__ Q,
    const unsigned short* __restrict__ mvp,
    const unsigned long long* __restrict__ MB,
    const uint8_t* __restrict__ Kbf, const uint8_t* __restrict__ Vtbf,
    float* __restrict__ out)
{
    extern __shared__ __align__(16) char lds[];
    const int tid  = threadIdx.x;
    const int lane = tid & 63;
    const int w    = tid >> 6;
    const int lq   = lane & 15;
    const int lk   = lane >> 4;

    // XCD-chunked remap: 8 XCDs x 64 blocks; 4 heads per XCD (KV L2-local).
    const int bid  = blockIdx.x;
    const int nbid = (bid & 7) * 64 + (bid >> 3);
    const int bh   = nbid >> 4;         // head 0..31
    const int j    = nbid & 15;         // pair: q-tiles j and 31-j
    const int b    = bh & (NBATCH - 1);

    const size_t ho = (size_t)bh * S_LEN * HDIM;
    const float* Qh = Q + ho;
    const uint8_t* kimg = Kbf  + (size_t)bh * 32 * 8192;
    const uint8_t* vimg = Vtbf + (size_t)bh * 32 * 8192;

    auto STAGE = [&](int img0, bool two, int bufb) {
        const uint8_t* gk = kimg + (size_t)img0 * 8192 + w * 2048 + lane * 16;
        const uint8_t* gv = vimg + (size_t)img0 * 8192 + w * 2048 + lane * 16;
        char* lk0 = &lds[bufb + w * 2048];
        char* lv0 = &lds[bufb + 16384 + w * 2048];
        load_lds16(gk,        lk0);
        load_lds16(gk + 1024, lk0 + 1024);
        load_lds16(gv,        lv0);
        load_lds16(gv + 1024, lv0 + 1024);
        if (two) {
            load_lds16(gk + 8192, lk0 + 8192);
            load_lds16(gk + 9216, lk0 + 9216);
            load_lds16(gv + 8192, lv0 + 8192);
            load_lds16(gv + 9216, lv0 + 9216);
        }
    };

    const int swz   = (lq & 7) << 4;
    const int pswz  = (lq & 15) << 4;
    const int pbase = 65536 + (w << 12);
    const int prow  = lq << 8;           // P row byte base (256 B rows)

    #pragma unroll 1
    for (int pass = 0; pass < 2; ++pass) {
        const int qb = pass ? (31 - j) : j;
        const int q0 = qb * 64;
        const int nt = (qb >> 1) + 1;    // 128-key iterations
        const int wqa = q0 + w * 16 + lq;

        // Q fragments (B-operand of swapped QK^T)
        bf16x8 qf[2];
        {
            const float* qrow = Qh + (size_t)(q0 + w * 16 + lq) * HDIM;
            #pragma unroll
            for (int c = 0; c < 2; ++c) {
                const int d0 = lk * 8 + c * 32;
                float4 f0 = *(const float4*)(qrow + d0);
                float4 f1 = *(const float4*)(qrow + d0 + 4);
                int4 qi;
                qi.x = cvt_pk_bf16(f0.x * QK_SCALE, f0.y * QK_SCALE);
                qi.y = cvt_pk_bf16(f0.z * QK_SCALE, f0.w * QK_SCALE);
                qi.z = cvt_pk_bf16(f1.x * QK_SCALE, f1.y * QK_SCALE);
                qi.w = cvt_pk_bf16(f1.z * QK_SCALE, f1.w * QK_SCALE);
                qf[c] = *(bf16x8*)&qi;
            }
        }

        f32x4 acc[4];
        #pragma unroll
        for (int g = 0; g < 4; ++g) acc[g] = (f32x4){0.f, 0.f, 0.f, 0.f};
        float m_r = 0.f;   // running max floor at 0: keeps fully-killed rows exact-zero
        float l_r = 0.f;

        STAGE(0, qb >= 1, 0);
        __syncthreads();

        for (int it = 0; it < nt; ++it) {
            const int kb     = (it & 1) << 15;
            const bool diag  = (it == nt - 1);
            const bool skipHi = diag && ((qb & 1) == 0);  // future half of last 128-tile
            if (!diag) {
                const int a = 2 * it + 2;
                STAGE(a, (a + 1) <= qb, kb ^ 32768);
            }

            // ---- QK^T swapped: S^T = mfma(A=K, B=Q); lane owns q=lq, keys 16g+4lk+r
            f32x4 sacc[8];
            #pragma unroll
            for (int g = 0; g < 8; ++g) sacc[g] = (f32x4){0.f, 0.f, 0.f, 0.f};
            __builtin_amdgcn_s_setprio(1);
            #pragma unroll
            for (int c = 0; c < 2; ++c) {
                #pragma unroll
                for (int g = 0; g < 4; ++g) {
                    bf16x8 kf = *(const bf16x8*)&lds[kb + ((16 * g + lq) * 128 + ((16 * lk + 64 * c) ^ swz))];
                    sacc[g] = __builtin_amdgcn_mfma_f32_16x16x32_bf16(kf, qf[c], sacc[g], 0, 0, 0);
                }
            }
            if (!skipHi) {
                #pragma unroll
                for (int c = 0; c < 2; ++c) {
                    #pragma unroll
                    for (int g = 4; g < 8; ++g) {
                        bf16x8 kf = *(const bf16x8*)&lds[kb + 8192 + ((16 * (g - 4) + lq) * 128 + ((16 * lk + 64 * c) ^ swz))];
                        sacc[g] = __builtin_amdgcn_mfma_f32_16x16x32_bf16(kf, qf[c], sacc[g], 0, 0, 0);
                    }
                }
            }
            __builtin_amdgcn_s_setprio(0);

            // ---- pre-max kill: causal (diag only) + key-padding mask
            if (diag) {
                const int wqrel = wqa - it * 128;
                #pragma unroll
                for (int g = 0; g < 8; ++g)
                    #pragma unroll
                    for (int r = 0; r < 4; ++r)
                        if (16 * g + 4 * lk + r > wqrel) sacc[g][r] = NEG_BIG;
            }
            const unsigned long long mb0 = MB[(b << 5) + 2 * it];
            const unsigned long long mb1 = MB[(b << 5) + 2 * it + 1];
            float mloc = NEG_BIG;
            #pragma unroll
            for (int g = 0; g < 8; ++g) {
                const unsigned long long mbw = (g < 4) ? mb0 : mb1;
                const unsigned int nib = (unsigned int)(mbw >> (16 * (g & 3) + 4 * lk)) & 0xFu;
                #pragma unroll
                for (int r = 0; r < 4; ++r) {
                    float s = ((nib >> r) & 1u) ? NEG_BIG : sacc[g][r];
                    sacc[g][r] = s;
                    mloc = fmaxf(mloc, s);
                }
            }
            mloc = fmaxf(mloc, __shfl_xor(mloc, 16, 64));
            mloc = fmaxf(mloc, __shfl_xor(mloc, 32, 64));

            // defer-max (T13)
            if (!__all(mloc - m_r <= DEFER_THR)) {
                const float newm = fmaxf(m_r, mloc);
                const float sc = exp2f(m_r - newm);
                l_r *= sc;
                m_r = newm;
                float scb[4];
                #pragma unroll
                for (int r = 0; r < 4; ++r) scb[r] = __shfl(sc, 4 * lk + r, 64);
                #pragma unroll
                for (int g = 0; g < 4; ++g)
                    #pragma unroll
                    for (int r = 0; r < 4; ++r) acc[g][r] *= scb[r];
            }

            // ---- exp + row-sum
            float ls0 = 0.f, ls1 = 0.f;
            #pragma unroll
            for (int g = 0; g < 8; ++g) {
                #pragma unroll
                for (int r = 0; r < 4; ++r) {
                    float e = exp2f(sacc[g][r] - m_r);
                    sacc[g][r] = e;
                    if (g & 1) ls1 += e; else ls0 += e;
                }
            }
            float ls = ls0 + ls1;
            ls += __shfl_xor(ls, 16, 64);
            ls += __shfl_xor(ls, 32, 64);
            l_r += ls;

            // ---- P write (wave-private, swizzled 256B rows)
            #pragma unroll
            for (int g = 0; g < 4; ++g) {
                uint2 pw;
                pw.x = cvt_pk_bf16(sacc[g][0], sacc[g][1]);
                pw.y = cvt_pk_bf16(sacc[g][2], sacc[g][3]);
                *(uint2*)&lds[pbase + prow + (((32 * g + 8 * lk)) ^ pswz)] = pw;
            }
            if (!skipHi) {
                #pragma unroll
                for (int g = 4; g < 8; ++g) {
                    uint2 pw;
                    pw.x = cvt_pk_bf16(sacc[g][0], sacc[g][1]);
                    pw.y = cvt_pk_bf16(sacc[g][2], sacc[g][3]);
                    *(uint2*)&lds[pbase + prow + (((32 * g + 8 * lk)) ^ pswz)] = pw;
                }
            }

            // ---- PV: O[q][d] += P[q][k] V[k][d]
            __builtin_amdgcn_s_setprio(1);
            #pragma unroll
            for (int c = 0; c < 2; ++c) {
                bf16x8 pa = *(const bf16x8*)&lds[pbase + prow + ((64 * c + 16 * lk) ^ pswz)];
                #pragma unroll
                for (int g = 0; g < 4; ++g) {
                    bf16x8 vb = *(const bf16x8*)&lds[kb + 16384 + ((lq + 16 * g) * 128 + ((16 * lk + 64 * c) ^ swz))];
                    acc[g] = __builtin_amdgcn_mfma_f32_16x16x32_bf16(pa, vb, acc[g], 0, 0, 0);
                }
            }
            if (!skipHi) {
                #pragma unroll
                for (int c = 2; c < 4; ++c) {
                    bf16x8 pa = *(const bf16x8*)&lds[pbase + prow + ((64 * c + 16 * lk) ^ pswz)];
                    #pragma unroll
                    for (int g = 0; g < 4; ++g) {
                        bf16x8 vb = *(const bf16x8*)&lds[kb + 16384 + 8192 + ((lq + 16 * g) * 128 + ((16 * lk + 64 * (c - 2)) ^ swz))];
                        acc[g] = __builtin_amdgcn_mfma_f32_16x16x32_bf16(pa, vb, acc[g], 0, 0, 0);
                    }
                }
            }
            __builtin_amdgcn_s_setprio(0);

            __syncthreads();
        }

        // ---- epilogue: dead rows (l==0: whole causal prefix masked) -> mean(V)
        float lr_b[4];
        #pragma unroll
        for (int r = 0; r < 4; ++r) lr_b[r] = __shfl(l_r, 4 * lk + r, 64);
        #pragma unroll
        for (int r = 0; r < 4; ++r) {
            const int qrow = q0 + w * 16 + 4 * lk + r;
            float* orow = out + ho + (size_t)qrow * HDIM;
            if (lr_b[r] == 0.f) {
                #pragma unroll
                for (int g = 0; g < 4; ++g) {
                    float s = 0.f;
                    for (int tt = 0; tt < 32; ++tt)
                        s += bf2f(mvp[(bh * 32 + tt) * 64 + lq + 16 * g]);
                    orow[lq + 16 * g] = s;
                }
            } else {
                const float inv = 1.0f / lr_b[r];
                #pragma unroll
                for (int g = 0; g < 4; ++g) orow[lq + 16 * g] = acc[g][r] * inv;
            }
        }
    }
}

extern "C" void kernel_launch(void* const* d_in, const int* in_sizes, int n_in,
                              void* d_out, int out_size, void* d_ws, size_t ws_size,
                              hipStream_t stream)
{
    const float* Q     = (const float*)d_in[0];
    const float* K     = (const float*)d_in[1];
    const float* V     = (const float*)d_in[2];
    const int*   masks = (const int*)d_in[3];
    float* out = (float*)d_out;

    char* ws = (char*)d_ws;
    unsigned long long* MB = (unsigned long long*)(ws + WS_MB);
    unsigned short* mvp    = (unsigned short*)(ws + WS_MVP);
    uint8_t* Kbf  = (uint8_t*)(ws + WS_KBF);
    uint8_t* Vtbf = (uint8_t*)(ws + WS_VTBF);

    hipFuncSetAttribute(reinterpret_cast<const void*>(&attn_fwd),
                        hipFuncAttributeMaxDynamicSharedMemorySize, 81920);

    cvt_kernel<<<dim3(1024), dim3(256), 0, stream>>>(K, V, masks, Kbf, Vtbf, mvp, MB);
    attn_fwd<<<dim3(512), dim3(256), 81920, stream>>>(Q, mvp, MB, Kbf, Vtbf, out);
}